// Round 8
// baseline (298.639 us; speedup 1.0000x reference)
//
#include <hip/hip_runtime.h>
#include <hip/hip_bf16.h>

#define N_TOKENS 16384
#define DIM      2048
#define NEXP     64
#define TOPK     8
#define LOSCALE  2048.0f      // 2^11, exact power of two
#define NBLOCKS  (N_TOKENS / 32)   // 512 blocks, 32 tokens each
#define BKC      128               // K chunk staged per barrier
#define ASTRIDE  136               // halves per row (128 + 8 pad)
#define LGSTRIDE 68

typedef _Float16 half8   __attribute__((ext_vector_type(8)));
typedef float    floatx4 __attribute__((ext_vector_type(4)));

// ---------------------------------------------------------------------------
// Kernel 0: split W (64x2048 fp32) into f16 hi/lo planes (L2-resident 512 KB).
// ---------------------------------------------------------------------------
__global__ __launch_bounds__(256) void wprep_kernel(const float* __restrict__ W,
                                                    _Float16* __restrict__ Whi,
                                                    _Float16* __restrict__ Wlo) {
    int i = blockIdx.x * 256 + threadIdx.x;           // grid 512 -> 131072
    float w = W[i];
    _Float16 h = (_Float16)w;
    Whi[i] = h;
    Wlo[i] = (_Float16)((w - (float)h) * LOSCALE);
}

// ---------------------------------------------------------------------------
// Fused kernel: MFMA router GEMM + softmax + top-8 + aux. Logits stay on-chip.
// R7 post-mortem: fragment-direct A loads are 16-line scattered -> latency-
// bound at 20% occupancy (114 us, MfmaUtil 4%). This version:
//   - 512 blocks x 512 threads; block owns 32 tokens, full K.
//   - 8 waves = 4 expert-slabs x 2 token-halves; each wave: 16 tok x 16 exp,
//     f16-split MFMA (a ~ ah + al/2^11; validated index-exact in R6/R7).
//   - Per BK=128 chunk: A staged COALESCED (16 lanes x 32 B per row),
//     f32->f16 hi/lo split ONCE during staging (not per expert-slab), LDS
//     stride 136 halves -> staging writes and ds_read_b128 fragment reads
//     both hit the optimal 8-cyc bank schedule. Register prefetch of the
//     next chunk overlaps the MFMA phase.
//   - B fragments direct from the L2-hot Whi/Wlo planes (8 loads/chunk/wave).
//   - Epilogue: logits -> LDS exchange; wave w ranks tokens [4w,4w+4);
//     rank_i = #{j: s_j>s_i or (s_j==s_i and j<i)} = lax.top_k semantics.
//   - aux: LDS reduce -> global atomics -> last-block ticket writes aux_loss.
// ---------------------------------------------------------------------------
__global__ __launch_bounds__(512) void moe_kernel(const float* __restrict__ A,
                                                  const _Float16* __restrict__ Whi,
                                                  const _Float16* __restrict__ Wlo,
                                                  float* __restrict__ out_w,
                                                  float* __restrict__ out_i,
                                                  float* __restrict__ out_aux,
                                                  float* __restrict__ cnt_ws,
                                                  float* __restrict__ sp_ws,
                                                  unsigned int* __restrict__ ticket) {
    __shared__ _Float16 Ahi[32 * ASTRIDE];
    __shared__ _Float16 Alo[32 * ASTRIDE];
    __shared__ float    lg_x[32 * LGSTRIDE];
    __shared__ float    s_cnt[NEXP];
    __shared__ float    s_sp[NEXP];
    __shared__ int      s_last;

    const int tid   = threadIdx.x;
    const int lane  = tid & 63;
    const int wv    = tid >> 6;          // 0..7
    const int slab  = wv & 3;            // expert slab (16 experts)
    const int th    = wv >> 2;           // token half (16 tokens)
    const int row16 = lane & 15;
    const int quad  = lane >> 4;
    const int tbase = blockIdx.x * 32;

    if (tid < NEXP) { s_cnt[tid] = 0.f; s_sp[tid] = 0.f; }

    // staging geometry: thread -> (row 0..31, 8-float column group 0..15)
    const int srow = tid >> 4;
    const int scg  = tid & 15;
    const float* aload = A + (size_t)(tbase + srow) * DIM + scg * 8;

    // fragment geometry
    const size_t boff = (size_t)(slab * 16 + row16) * DIM + quad * 8;
    _Float16* ahw = Ahi + srow * ASTRIDE + scg * 8;
    _Float16* alw = Alo + srow * ASTRIDE + scg * 8;
    const _Float16* ahr = Ahi + (th * 16 + row16) * ASTRIDE + quad * 8;
    const _Float16* alr = Alo + (th * 16 + row16) * ASTRIDE + quad * 8;

    floatx4 acc0 = {};   // hi*hi
    floatx4 acc1 = {};   // hi*lo_s + lo_s*hi (carries 2^11)

    float4 ar0 = *(const float4*)(aload);
    float4 ar1 = *(const float4*)(aload + 4);

    for (int c = 0; c < DIM / BKC; ++c) {
        // convert this chunk's staged registers and write f16 planes
        {
            float v[8] = {ar0.x, ar0.y, ar0.z, ar0.w, ar1.x, ar1.y, ar1.z, ar1.w};
            half8 h, l;
            #pragma unroll
            for (int j = 0; j < 8; ++j) {
                _Float16 hh = (_Float16)v[j];
                h[j] = hh;
                l[j] = (_Float16)((v[j] - (float)hh) * LOSCALE);
            }
            *(half8*)ahw = h;
            *(half8*)alw = l;
        }
        __syncthreads();

        // prefetch next chunk's A while this chunk computes
        if (c + 1 < DIM / BKC) {
            ar0 = *(const float4*)(aload + (c + 1) * BKC);
            ar1 = *(const float4*)(aload + (c + 1) * BKC + 4);
        }

        // compute: 4 sub-chunks of 32 k
        const _Float16* bbase = Whi + boff + c * BKC;
        const _Float16* bbasl = Wlo + boff + c * BKC;
        #pragma unroll
        for (int kk = 0; kk < 4; ++kk) {
            half8 bh = *(const half8*)(bbase + kk * 32);
            half8 bl = *(const half8*)(bbasl + kk * 32);
            half8 ah = *(const half8*)(ahr + kk * 32);
            half8 al = *(const half8*)(alr + kk * 32);
            acc0 = __builtin_amdgcn_mfma_f32_16x16x32_f16(ah, bh, acc0, 0, 0, 0);
            acc1 = __builtin_amdgcn_mfma_f32_16x16x32_f16(ah, bl, acc1, 0, 0, 0);
            acc1 = __builtin_amdgcn_mfma_f32_16x16x32_f16(al, bh, acc1, 0, 0, 0);
        }
        __syncthreads();
    }

    // logits -> LDS exchange; C layout: col=lane&15 (expert), row=quad*4+reg
    const float inv = 1.0f / LOSCALE;
    #pragma unroll
    for (int reg = 0; reg < 4; ++reg) {
        int tok = th * 16 + quad * 4 + reg;
        lg_x[tok * LGSTRIDE + slab * 16 + row16] = acc0[reg] + acc1[reg] * inv;
    }
    __syncthreads();

    // epilogue: wave wv handles tokens [wv*4, wv*4+4); lane = expert
    float sp = 0.f, cnt = 0.f;
    #pragma unroll
    for (int i = 0; i < 4; ++i) {
        int t = wv * 4 + i;
        float lg = lg_x[t * LGSTRIDE + lane];

        float m = lg;
        #pragma unroll
        for (int off = 32; off; off >>= 1) m = fmaxf(m, __shfl_xor(m, off));
        float e = expf(lg - m);
        float ssum = e;
        #pragma unroll
        for (int off = 32; off; off >>= 1) ssum += __shfl_xor(ssum, off);
        float score = e / ssum;
        sp += score;

        int rank = 0;
        #pragma unroll
        for (int j = 0; j < 64; ++j) {
            float sj = __shfl(score, j);
            rank += (sj > score) || (sj == score && j < lane);
        }
        bool sel = rank < TOPK;

        float v = sel ? score : 0.f;
        #pragma unroll
        for (int off = 32; off; off >>= 1) v += __shfl_xor(v, off);

        if (sel) {
            out_w[(size_t)(tbase + t) * TOPK + rank] = score / v;
            out_i[(size_t)(tbase + t) * TOPK + rank] = (float)lane;
            cnt += 1.f;
        }
    }

    atomicAdd(&s_sp[lane], sp);
    atomicAdd(&s_cnt[lane], cnt);
    __syncthreads();
    if (tid < 64)       atomicAdd(&cnt_ws[tid], s_cnt[tid]);
    else if (tid < 128) atomicAdd(&sp_ws[tid - 64], s_sp[tid - 64]);

    __threadfence();
    __syncthreads();
    if (tid == 0)
        s_last = (atomicAdd(ticket, 1u) == (unsigned)(gridDim.x - 1));
    __syncthreads();
    if (s_last && tid < 64) {
        float cc = atomicAdd(&cnt_ws[tid], 0.f);   // device-scope read
        float pp = atomicAdd(&sp_ws[tid], 0.f);
        float v = (cc / (float)(N_TOKENS * TOPK)) * (pp / (float)N_TOKENS);
        #pragma unroll
        for (int off = 32; off; off >>= 1) v += __shfl_xor(v, off);
        if (tid == 0) out_aux[0] = 0.001f * (float)NEXP * v;
    }
}

extern "C" void kernel_launch(void* const* d_in, const int* in_sizes, int n_in,
                              void* d_out, int out_size, void* d_ws, size_t ws_size,
                              hipStream_t stream) {
    const float* A = (const float*)d_in[0];   // hidden_states (16384 x 2048)
    const float* W = (const float*)d_in[1];   // weight        (64 x 2048)
    float* out = (float*)d_out;

    _Float16*     whi    = (_Float16*)d_ws;
    _Float16*     wlo    = whi + (size_t)NEXP * DIM;
    float*        cnt_ws = (float*)(wlo + (size_t)NEXP * DIM);
    float*        sp_ws  = cnt_ws + NEXP;
    unsigned int* ticket = (unsigned int*)(sp_ws + NEXP);

    hipMemsetAsync(cnt_ws, 0, 2 * NEXP * sizeof(float) + sizeof(unsigned int), stream);

    hipLaunchKernelGGL(wprep_kernel, dim3(NEXP * DIM / 256), dim3(256), 0, stream,
                       W, whi, wlo);

    float* out_w = out;
    float* out_i = out + (size_t)N_TOKENS * TOPK;
    float* out_a = out + 2 * (size_t)N_TOKENS * TOPK;

    hipLaunchKernelGGL(moe_kernel, dim3(NBLOCKS), dim3(512), 0, stream,
                       A, whi, wlo, out_w, out_i, out_a, cnt_ws, sp_ws, ticket);
}